// Round 11
// baseline (53.611 us; speedup 1.0000x reference)
//
#include <hip/hip_runtime.h>
#include <stdint.h>

typedef __attribute__((ext_vector_type(4))) float  f32x4;
typedef __attribute__((ext_vector_type(8))) __bf16 bf16x8;

#define NB   32
#define CC   512
#define DD   512
#define HW   1024
#define NKS  16      // K-steps of 32

#define WAITL()  asm volatile("s_waitcnt lgkmcnt(0)" ::: "memory")
#define BARR()   do { asm volatile("" ::: "memory"); __builtin_amdgcn_s_barrier(); \
                      asm volatile("" ::: "memory"); } while (0)

// Fused softmax + batched GEMM: out[n] = softmax(atts[n]) @ images[n]
// Register-envelope design: wave tile 128x32 -> acc[8][2] = 64 AGPR; B operand
// loaded DIRECTLY in MFMA B-fragment layout (no LDS for B at all); A staged
// JIT (exp on the fly) into a tiny 20KB dbuf. Total regs ~128 -> 4 waves/SIMD,
// 2 blocks/CU (grid 512), 16 waves/CU = 2x R9's TLP.
__global__ __launch_bounds__(512, 4) void fused_kernel(
        const float* __restrict__ images, const float* __restrict__ atts,
        float* __restrict__ out) {
    __shared__ unsigned short lA[2][128][40];       // 20KB, 16B-aligned slots
    __shared__ float2 lStats[128];                  // 1KB

    const int b  = blockIdx.x;       // 0..511
    const int g  = b & 7;            // XCD
    const int q  = b >> 3;           // 0..63
    const int n  = (q >> 4) * 8 + g; // batch 0..31, n%8 == XCD
    const int rt = (q >> 2) & 3;     // row tile 0..3 (128 rows)
    const int ct = q & 3;            // col tile 0..3 (256 cols)

    const int tid  = threadIdx.x;
    const int lane = tid & 63;
    const int w    = tid >> 6;       // wave 0..7 -> cols ct*256 + w*32
    const int r15  = lane & 15;
    const int kgl  = lane >> 4;

    const float* gAt = atts + (size_t)n * CC * DD + (size_t)(rt * 128) * DD;
    const float* gB  = images + (size_t)n * DD * HW + ct * 256 + w * 32;
    float*       gO  = out + (size_t)n * CC * HW + (size_t)(rt * 128) * HW
                           + ct * 256 + w * 32;

    // ---- phase 0: in-block softmax stats (R9 pattern: 32 groups x 4 rows) ----
    {
        const int grp = tid >> 4;    // 0..31
        const int l16 = tid & 15;
        #pragma unroll
        for (int s = 0; s < 4; ++s) {
            const int row = grp * 4 + s;             // 0..127
            const float* ap = gAt + (size_t)row * DD + l16 * 32;
            f32x4 v[8];
            #pragma unroll
            for (int j = 0; j < 8; ++j) v[j] = *(const f32x4*)(ap + j * 4);
            float m = v[0][0];
            #pragma unroll
            for (int j = 0; j < 8; ++j)
                #pragma unroll
                for (int c = 0; c < 4; ++c) m = fmaxf(m, v[j][c]);
            #pragma unroll
            for (int k = 1; k < 16; k <<= 1) m = fmaxf(m, __shfl_xor(m, k, 16));
            float sum = 0.f;
            #pragma unroll
            for (int j = 0; j < 8; ++j)
                #pragma unroll
                for (int c = 0; c < 4; ++c) sum += __expf(v[j][c] - m);
            #pragma unroll
            for (int k = 1; k < 16; k <<= 1) sum += __shfl_xor(sum, k, 16);
            if (l16 == 0) lStats[row] = make_float2(m, 1.0f / sum);
        }
    }
    WAITL();
    BARR();

    // A staging coords: thread covers row tid>>2, 16B slot tid&3 (8 f32)
    const int arow = tid >> 2;
    const int aq   = tid & 3;
    const float2 st = lStats[arow];  // (row max, 1/sum)

    f32x4 acc[8][2] = {};
    f32x4 areg[2];                   // atts prefetch (8 f32)
    float bA[16], bB[16];            // two B dword sets (2-step flight)

    auto loadAt = [&](int kt) {
        const float* p = gAt + (size_t)arow * DD + kt * 32 + aq * 8;
        areg[0] = *(const f32x4*)p;
        areg[1] = *(const f32x4*)(p + 4);
    };
    auto stageA = [&](int buf) {     // exp + cvt + one 16B ds_write
        bf16x8 wv;
        #pragma unroll
        for (int e = 0; e < 8; ++e) {
            const float x = areg[e >> 2][e & 3];
            wv[e] = (__bf16)(__expf(x - st.x) * st.y);
        }
        *(bf16x8*)&lA[buf][arow][aq * 8] = wv;
    };
    // B in MFMA B-frag layout: lane (kgl,r15) -> k = kgl*8+e, col = nf*16+r15
    auto loadB = [&](int kt, float (&d)[16]) {
        const float* p = gB + (size_t)(kt * 32 + kgl * 8) * HW + r15;
        #pragma unroll
        for (int nf = 0; nf < 2; ++nf)
            #pragma unroll
            for (int e = 0; e < 8; ++e)
                d[nf * 8 + e] = p[(size_t)e * HW + nf * 16];
    };
    auto compute = [&](int buf, const float (&d)[16]) {
        bf16x8 bv[2];
        #pragma unroll
        for (int nf = 0; nf < 2; ++nf)
            #pragma unroll
            for (int e = 0; e < 8; ++e)
                bv[nf][e] = (__bf16)d[nf * 8 + e];
        #pragma unroll
        for (int m = 0; m < 8; ++m) {
            const bf16x8 af = *(const bf16x8*)&lA[buf][m * 16 + r15][kgl * 8];
            acc[m][0] = __builtin_amdgcn_mfma_f32_16x16x32_bf16(af, bv[0], acc[m][0], 0, 0, 0);
            acc[m][1] = __builtin_amdgcn_mfma_f32_16x16x32_bf16(af, bv[1], acc[m][1], 0, 0, 0);
        }
    };

    // ---- prologue ----
    loadB(0, bA);
    loadAt(0);
    stageA(0);                       // waits areg(0), writes lA[0]
    loadB(1, bB);
    loadAt(1);                       // areg = atts(1)
    WAITL();
    BARR();

    // ---- K-loop: one barrier per step; B 2 steps in flight; A 1 step ----
    #pragma unroll
    for (int kt = 0; kt < NKS; ++kt) {
        const int cur = kt & 1, nxt = cur ^ 1;
        if (kt + 1 < NKS) stageA(nxt);       // consumes areg = atts(kt+1)
        if (kt + 2 < NKS) loadAt(kt + 2);    // refill areg
        if (kt & 1) {
            compute(cur, bB);
            if (kt + 2 < NKS) loadB(kt + 2, bB);
        } else {
            compute(cur, bA);
            if (kt + 2 < NKS) loadB(kt + 2, bA);
        }
        if (kt + 1 < NKS) { WAITL(); BARR(); }
    }

    // ---- epilogue: C/D layout col=lane&15, row=(lane>>4)*4+r ----
    #pragma unroll
    for (int m = 0; m < 8; ++m)
        #pragma unroll
        for (int nf = 0; nf < 2; ++nf)
            #pragma unroll
            for (int r = 0; r < 4; ++r) {
                const int row = m * 16 + kgl * 4 + r;
                const int col = nf * 16 + r15;
                gO[(size_t)row * HW + col] = acc[m][nf][r];
            }
}

extern "C" void kernel_launch(void* const* d_in, const int* in_sizes, int n_in,
                              void* d_out, int out_size, void* d_ws, size_t ws_size,
                              hipStream_t stream) {
    const float* images = (const float*)d_in[0];
    const float* atts   = (const float*)d_in[1];
    float*       out    = (float*)d_out;

    fused_kernel<<<dim3(512), dim3(512), 0, stream>>>(images, atts, out);
}

// Round 12
// 34.450 us; speedup vs baseline: 1.5562x; 1.5562x over previous
//
#include <hip/hip_runtime.h>
#include <stdint.h>

typedef __attribute__((ext_vector_type(4))) float  f32x4;
typedef __attribute__((ext_vector_type(8))) __bf16 bf16x8;

#define NB   32
#define CC   512
#define DD   512
#define HW   1024
#define NKS  16      // K-steps of 32

#define WAITL()  asm volatile("s_waitcnt lgkmcnt(0)" ::: "memory")
#define BARR()   do { asm volatile("" ::: "memory"); __builtin_amdgcn_s_barrier(); \
                      asm volatile("" ::: "memory"); } while (0)

// Fused softmax + batched GEMM: out[n] = softmax(atts[n]) @ images[n]
// R9 structure (best so far) + three surgical fixes:
//  1. phase-1 A-panel writes: lane covers chunks q = p*16+l16 (stride-16)
//     -> slot&7 spreads over l16 -> 2-way banks (was 8-way, 1.8M conflicts)
//  2. lB plane map slot(c) = (c&3)*16 + ((c>>2) ^ ((c&3)<<2)): 2-way on both
//     ds_write and ds_read (old map read back 4-way)
//  3. two breg sets: B tile kt+2 issued at iter kt -> full-iteration flight
__global__ __launch_bounds__(512, 2) void fused_kernel(
        const float* __restrict__ images, const float* __restrict__ atts,
        float* __restrict__ out) {
    __shared__ unsigned short lA[128][512];         // 128KB [row][chunk^row&7]
    __shared__ unsigned short lB[8][4][64][8];      // 32KB  wave/kgl planes

    const int b  = blockIdx.x;       // 0..255
    const int g  = b & 7;            // XCD
    const int q  = b >> 3;           // 0..31
    const int n  = (q & 3) * 8 + g;  // batch, n%8 == XCD
    const int t  = q >> 2;           // 0..7
    const int rt = t & 3;            // row tile 0..3 (128 rows)
    const int ct = t >> 2;           // col tile 0..1 (512 cols)

    const int tid  = threadIdx.x;
    const int lane = tid & 63;
    const int w    = tid >> 6;       // wave 0..7 -> cols ct*512 + w*64
    const int r15  = lane & 15;
    const int kgl  = lane >> 4;

    const float* gAt = atts + (size_t)n * CC * DD + (size_t)(rt * 128) * DD;
    const float* gB  = images + (size_t)n * DD * HW + ct * 512 + w * 64;
    float*       gO  = out + (size_t)n * CC * HW + (size_t)(rt * 128) * HW
                           + ct * 512 + w * 64;

    // ---- phase 1: softmax fill. 32 groups of 16 lanes; 4 rows each ----
    {
        const int grp = tid >> 4;    // 0..31
        const int l16 = tid & 15;
        for (int s = 0; s < 4; ++s) {
            const int row = grp * 4 + s;             // 0..127
            const float* ap = gAt + (size_t)row * DD;
            f32x4 v[8];
            #pragma unroll
            for (int p = 0; p < 4; ++p) {            // chunk q = p*16+l16
                v[2*p]   = *(const f32x4*)(ap + (p * 16 + l16) * 8);
                v[2*p+1] = *(const f32x4*)(ap + (p * 16 + l16) * 8 + 4);
            }
            float m = v[0][0];
            #pragma unroll
            for (int j = 0; j < 8; ++j)
                #pragma unroll
                for (int c = 0; c < 4; ++c) m = fmaxf(m, v[j][c]);
            #pragma unroll
            for (int k = 1; k < 16; k <<= 1) m = fmaxf(m, __shfl_xor(m, k, 16));
            float sum = 0.f;
            #pragma unroll
            for (int j = 0; j < 8; ++j)
                #pragma unroll
                for (int c = 0; c < 4; ++c) {
                    v[j][c] = __expf(v[j][c] - m);
                    sum += v[j][c];
                }
            #pragma unroll
            for (int k = 1; k < 16; k <<= 1) sum += __shfl_xor(sum, k, 16);
            const float inv = 1.0f / sum;
            #pragma unroll
            for (int p = 0; p < 4; ++p) {            // 2-way write banks
                bf16x8 wv;
                #pragma unroll
                for (int e = 0; e < 8; ++e)
                    wv[e] = (__bf16)(v[2*p + (e >> 2)][e & 3] * inv);
                const int slot = (p * 16 + l16) ^ (row & 7);
                *(bf16x8*)&lA[row][slot * 8] = wv;
            }
        }
    }
    WAITL();
    BARR();                          // the ONLY barrier in the kernel

    f32x4 acc[8][4] = {};
    f32x4 bA[8], bB[8];              // two B reg sets (2-iter flight)

    auto loadB = [&](int kt, f32x4 (&d)[8]) {
        const float* p = gB + (size_t)(kt * 32 + kgl * 8) * HW + r15 * 4;
        #pragma unroll
        for (int j = 0; j < 8; ++j)
            d[j] = *(const f32x4*)(p + (size_t)j * HW);
    };
    // lB plane map: slot(c) = (c&3)*16 + ((c>>2) ^ ((c&3)<<2)); 2-way banks
    auto writeB = [&](const f32x4 (&d)[8]) {
        #pragma unroll
        for (int cc = 0; cc < 4; ++cc) {
            bf16x8 wv;
            #pragma unroll
            for (int j = 0; j < 8; ++j) wv[j] = (__bf16)d[j][cc];
            const int slot = cc * 16 + (r15 ^ (cc << 2));
            *(bf16x8*)&lB[w][kgl][slot][0] = wv;
        }
    };
    auto compute = [&](int kt) {
        bf16x8 af[8], bv[4];
        #pragma unroll
        for (int m = 0; m < 8; ++m) {
            const int slot = ((kt << 2) + kgl) ^ (r15 & 7);
            af[m] = *(const bf16x8*)&lA[m * 16 + r15][slot * 8];
        }
        #pragma unroll
        for (int nf = 0; nf < 4; ++nf) {
            const int c    = nf * 16 + r15;
            const int slot = (c & 3) * 16 + (((c >> 2) ^ ((c & 3) << 2)) & 15);
            bv[nf] = *(const bf16x8*)&lB[w][kgl][slot][0];
        }
        #pragma unroll
        for (int m = 0; m < 8; ++m)
            #pragma unroll
            for (int nf = 0; nf < 4; ++nf)
                acc[m][nf] = __builtin_amdgcn_mfma_f32_16x16x32_bf16(
                    af[m], bv[nf], acc[m][nf], 0, 0, 0);
    };

    // ---- phase 2: barrier-free K-loop, B two tiles in flight ----
    loadB(0, bA);
    loadB(1, bB);
    writeB(bA);                      // waits bA(0); plane <- tile 0
    #pragma unroll
    for (int kt = 0; kt < NKS; ++kt) {
        compute(kt);                 // plane holds tile kt
        if (kt + 1 < NKS) {
            if (kt & 1) {            // tile kt+1 sits in set[(kt+1)&1]
                writeB(bA);
                if (kt + 2 < NKS) loadB(kt + 2, bB);   // refill consumed set
            } else {
                writeB(bB);
                if (kt + 2 < NKS) loadB(kt + 2, bA);
            }
        }
    }

    // ---- epilogue: C/D layout col=lane&15, row=(lane>>4)*4+r ----
    #pragma unroll
    for (int m = 0; m < 8; ++m)
        #pragma unroll
        for (int nf = 0; nf < 4; ++nf)
            #pragma unroll
            for (int r = 0; r < 4; ++r) {
                const int row = m * 16 + kgl * 4 + r;
                const int col = nf * 16 + r15;
                gO[(size_t)row * HW + col] = acc[m][nf][r];
            }
}

extern "C" void kernel_launch(void* const* d_in, const int* in_sizes, int n_in,
                              void* d_out, int out_size, void* d_ws, size_t ws_size,
                              hipStream_t stream) {
    const float* images = (const float*)d_in[0];
    const float* atts   = (const float*)d_in[1];
    float*       out    = (float*)d_out;

    fused_kernel<<<dim3(NB * 8), dim3(512), 0, stream>>>(images, atts, out);
}